// Round 1
// baseline (197.926 us; speedup 1.0000x reference)
//
#include <hip/hip_runtime.h>
#include <cstdint>
#include <cstddef>

#define NUM_LAYERS 20
#define HID 1024
#define M_TOTAL 8192
#define K_DIM 1024
#define N_DIM 1024

typedef __attribute__((ext_vector_type(8))) short bf16x8;
typedef __attribute__((ext_vector_type(4))) float floatx4;

typedef __attribute__((address_space(1))) unsigned int as1_u32;
typedef __attribute__((address_space(3))) unsigned int as3_u32;

__device__ __forceinline__ unsigned short f2bf(float f) {
  union { float f; unsigned int u; } v; v.f = f;
  unsigned int r = v.u + 0x7fffu + ((v.u >> 16) & 1u);  // round-to-nearest-even
  return (unsigned short)(r >> 16);
}

// async global->LDS, 16B per lane; lds ptr must be wave-uniform base (HW adds lane*16)
__device__ __forceinline__ void load16_lds(const void* g, void* l) {
  __builtin_amdgcn_global_load_lds(
      reinterpret_cast<as1_u32*>(reinterpret_cast<uintptr_t>(g)),
      reinterpret_cast<as3_u32*>(reinterpret_cast<uintptr_t>(l)),
      16, 0, 0);
}

// ---- Kernel 1: x fp32 -> bf16 ----
__global__ __launch_bounds__(256) void xcast_kernel(const float* __restrict__ x,
                                                    unsigned short* __restrict__ xb) {
  int idx = blockIdx.x * 256 + threadIdx.x;  // 4 floats per thread
  const float4 v = reinterpret_cast<const float4*>(x)[idx];
  ushort4 o;
  o.x = f2bf(v.x); o.y = f2bf(v.y); o.z = f2bf(v.z); o.w = f2bf(v.w);
  reinterpret_cast<ushort4*>(xb)[idx] = o;
}

// ---- Kernel 2: sum 20 conv layers (fp32 accumulate) -> bf16, [N][K] K-contiguous ----
__global__ __launch_bounds__(256) void wsum_kernel(const float* __restrict__ w,
                                                   unsigned short* __restrict__ wb) {
  int idx = blockIdx.x * 256 + threadIdx.x;  // 4 floats per thread
  float4 s = make_float4(0.f, 0.f, 0.f, 0.f);
  const float4* p = reinterpret_cast<const float4*>(w) + idx;
#pragma unroll
  for (int l = 0; l < NUM_LAYERS; ++l) {
    float4 v = p[(size_t)l * (HID * HID / 4)];
    s.x += v.x; s.y += v.y; s.z += v.z; s.w += v.w;
  }
  ushort4 o;
  o.x = f2bf(s.x); o.y = f2bf(s.y); o.z = f2bf(s.z); o.w = f2bf(s.w);
  reinterpret_cast<ushort4*>(wb)[idx] = o;
}

// ---- Kernel 3: GEMM C[M][N] = (A[M][K] @ B[N][K]^T) * (1/20), bf16 MFMA ----
// 128x128 tile, BK=32, 256 threads = 4 waves, each wave 64x64 (4x4 of 16x16x32)
__global__ __launch_bounds__(256) void gemm_kernel(const unsigned short* __restrict__ A,
                                                   const unsigned short* __restrict__ B,
                                                   float* __restrict__ C) {
  __shared__ unsigned short lA[128 * 32];
  __shared__ unsigned short lB[128 * 32];

  const int tid = threadIdx.x;
  const int lane = tid & 63;
  const int wave = tid >> 6;
  const int wr = wave >> 1;    // 0..1
  const int wc = wave & 1;     // 0..1
  const int quad = lane >> 4;  // 0..3
  const int mrow = lane & 15;

  const int bid = blockIdx.x;
  const int nb = bid & 7;      // 8 N-blocks; consecutive bids share mb -> A reuse in L2/L3
  const int mb = bid >> 3;

  // staging: thread t loads 8 bf16 (16 B) from row (t>>2), k-offset (t&3)*8
  const int srow = tid >> 2;
  const int skoff = (tid & 3) * 8;
  const unsigned short* gA = A + (size_t)(mb * 128 + srow) * K_DIM + skoff;
  const unsigned short* gB = B + (size_t)(nb * 128 + srow) * K_DIM + skoff;

  // wave-uniform LDS bases: each issue = 256 threads * 16 B = 4 KiB = 64 rows
  unsigned short* lA0 = lA + wave * 512;
  unsigned short* lA1 = lA + 2048 + wave * 512;
  unsigned short* lB0 = lB + wave * 512;
  unsigned short* lB1 = lB + 2048 + wave * 512;

  floatx4 acc[4][4] = {};

  // fragment read bases (row-major [row][32], 16B-aligned chunks)
  const unsigned short* ra[4];
  const unsigned short* rb[4];
#pragma unroll
  for (int i = 0; i < 4; ++i) {
    ra[i] = lA + (wr * 64 + i * 16 + mrow) * 32 + quad * 8;
    rb[i] = lB + (wc * 64 + i * 16 + mrow) * 32 + quad * 8;
  }

  for (int k0 = 0; k0 < K_DIM; k0 += 32) {
    __syncthreads();  // previous iter's ds_reads done before overwrite
    load16_lds(gA, lA0);
    load16_lds(gA + (size_t)64 * K_DIM, lA1);
    load16_lds(gB, lB0);
    load16_lds(gB + (size_t)64 * K_DIM, lB1);
    gA += 32;
    gB += 32;
    __syncthreads();  // staging complete (compiler drains vmcnt before barrier)

    bf16x8 af[4], bfr[4];
#pragma unroll
    for (int i = 0; i < 4; ++i) af[i] = *reinterpret_cast<const bf16x8*>(ra[i]);
#pragma unroll
    for (int j = 0; j < 4; ++j) bfr[j] = *reinterpret_cast<const bf16x8*>(rb[j]);
#pragma unroll
    for (int i = 0; i < 4; ++i)
#pragma unroll
      for (int j = 0; j < 4; ++j)
        acc[i][j] = __builtin_amdgcn_mfma_f32_16x16x32_bf16(af[i], bfr[j], acc[i][j], 0, 0, 0);
  }

  // epilogue: C/D layout col=lane&15, row=quad*4+reg
  const float scale = 1.0f / NUM_LAYERS;
  const int row_base = mb * 128 + wr * 64 + quad * 4;
  const int col_base = nb * 128 + wc * 64 + mrow;
#pragma unroll
  for (int i = 0; i < 4; ++i) {
#pragma unroll
    for (int j = 0; j < 4; ++j) {
#pragma unroll
      for (int r = 0; r < 4; ++r) {
        int row = row_base + i * 16 + r;
        C[(size_t)row * N_DIM + col_base + j * 16] = acc[i][j][r] * scale;
      }
    }
  }
}

// ---- Kernel 4: in-place RMS norm per row: y = x * 32 * rsqrt(sum x^2 + eps*H) * norm_w ----
__global__ __launch_bounds__(256) void rmsnorm_kernel(float* __restrict__ out,
                                                      const float* __restrict__ nw) {
  const int row = blockIdx.x;
  const int tid = threadIdx.x;
  float4* p = reinterpret_cast<float4*>(out + (size_t)row * HID);
  float4 v = p[tid];
  float ss = v.x * v.x + v.y * v.y + v.z * v.z + v.w * v.w;
#pragma unroll
  for (int off = 32; off > 0; off >>= 1) ss += __shfl_down(ss, off, 64);
  __shared__ float wss[4];
  if ((tid & 63) == 0) wss[tid >> 6] = ss;
  __syncthreads();
  float tot = wss[0] + wss[1] + wss[2] + wss[3];
  float scale = 32.0f * rsqrtf(tot + 1.024e-3f);  // sqrt(1024)=32, EPS*H=1.024e-3
  float4 w = reinterpret_cast<const float4*>(nw)[tid];
  v.x *= scale * w.x; v.y *= scale * w.y; v.z *= scale * w.z; v.w *= scale * w.w;
  p[tid] = v;
}

extern "C" void kernel_launch(void* const* d_in, const int* in_sizes, int n_in,
                              void* d_out, int out_size, void* d_ws, size_t ws_size,
                              hipStream_t stream) {
  const float* x = (const float*)d_in[0];       // [2,4096,1024] fp32
  const float* conv_w = (const float*)d_in[1];  // [20,1024,1024] fp32
  const float* norm_w = (const float*)d_in[2];  // [1024] fp32
  float* out = (float*)d_out;                   // [2,4096,1024] fp32

  unsigned short* xb = (unsigned short*)d_ws;                                   // 16 MiB
  unsigned short* wb = (unsigned short*)((char*)d_ws + (size_t)M_TOTAL * K_DIM * 2);  // +2 MiB

  xcast_kernel<<<(M_TOTAL * K_DIM) / (4 * 256), 256, 0, stream>>>(x, xb);
  wsum_kernel<<<(HID * HID) / (4 * 256), 256, 0, stream>>>(conv_w, wb);
  gemm_kernel<<<(M_TOTAL / 128) * (N_DIM / 128), 256, 0, stream>>>(xb, wb, out);
  rmsnorm_kernel<<<M_TOTAL, 256, 0, stream>>>(out, norm_w);
}